// Round 9
// baseline (199.079 us; speedup 1.0000x reference)
//
#include <hip/hip_runtime.h>

// Problem constants (B=4, S=2048 -> T=8192 tokens; H=1024; E=8 experts)
constexpr int kT = 8192;
constexpr int kH = 1024;
constexpr int kE = 8;
constexpr int kMaxTiles = 72;     // kT/128 + kE
constexpr int kCntStride = 32;    // pad expert counters to separate 128B cache lines

typedef short short8 __attribute__((ext_vector_type(8)));
typedef float floatx4 __attribute__((ext_vector_type(4)));

__device__ inline unsigned short f2b(float f) {
    union { float f; unsigned int u; } v; v.f = f;
    unsigned int r = v.u + 0x7FFFu + ((v.u >> 16) & 1u);  // round-to-nearest-even
    return (unsigned short)(r >> 16);
}

#define GLDS16(gp, lp)                                                                  \
    __builtin_amdgcn_global_load_lds(                                                   \
        (const __attribute__((address_space(1))) unsigned int*)(gp),                    \
        (__attribute__((address_space(3))) unsigned int*)(lp), 16, 0, 0)

// ---------------- K1: FUSED prep (R16) ----------------
// R16 post-mortem of R15: paired-token router blew VGPR 32->168 (occupancy 54%->9%,
// prep 33->47us) — occupancy is the binding resource in this latency-bound kernel,
// NOT per-token instruction count. Revert router to the R14/R7 body (~32 VGPR) and
// add __launch_bounds__(256,4) as a VGPR cap (<=128) so codegen can't regress this
// way again. bid [0,1024) = transpose (R14 wide-LDS body), [1024,2048) = router
// (8 tokens/block, 2/wave).
__global__ __launch_bounds__(256, 4) void k_prep(const float* __restrict__ W,
                                                 unsigned short* __restrict__ Wt,
                                                 const float* __restrict__ x,
                                                 unsigned short* __restrict__ xb,
                                                 const float* __restrict__ rw,
                                                 const float* __restrict__ rb,
                                                 float* __restrict__ gate,
                                                 int* __restrict__ idx,
                                                 int* __restrict__ cnt) {
    __shared__ __align__(16) char smem[32768];
    int bid = blockIdx.x, tid = threadIdx.x;
    if (bid == 0 && tid < kE) cnt[tid * kCntStride] = 0;   // zero padded counters
    if (bid < 1024) {
        // ---- transpose path: 64k x 128n per block (R14 wide-LDS scheme) ----
        unsigned int* ldsw = (unsigned int*)smem;   // [128][32] dwords, swizzled (16KB)
        int tb = bid;
        int e = tb >> 7, kb = (tb >> 3) & 15, nb2 = tb & 7;
        const float* Wp = W + ((size_t)e << 20) + (size_t)(kb * 64) * kH + nb2 * 128;
        int c = (tid & 31) * 4;                  // n base (0..124)
        int rr = tid >> 5;                       // 0..7 (8-k slab)
        unsigned int dw[4][4];                   // [i = k-pair][j = n offset]
#pragma unroll
        for (int i = 0; i < 4; ++i) {
            int r0 = rr * 8 + i * 2;
            float4 v0 = *(const float4*)(Wp + (size_t)r0 * kH + c);
            float4 v1 = *(const float4*)(Wp + (size_t)(r0 + 1) * kH + c);
            dw[i][0] = (unsigned int)f2b(v0.x) | ((unsigned int)f2b(v1.x) << 16);
            dw[i][1] = (unsigned int)f2b(v0.y) | ((unsigned int)f2b(v1.y) << 16);
            dw[i][2] = (unsigned int)f2b(v0.z) | ((unsigned int)f2b(v1.z) << 16);
            dw[i][3] = (unsigned int)f2b(v0.w) | ((unsigned int)f2b(v1.w) << 16);
        }
#pragma unroll
        for (int j = 0; j < 4; ++j) {
            int n = c + j;
            int key = ((n ^ (n >> 3)) & 7) << 2;
            uint4 q{dw[0][j], dw[1][j], dw[2][j], dw[3][j]};   // logical dw rr*4..+3
            *(uint4*)&ldsw[n * 32 + ((rr * 4) ^ key)] = q;     // ds_write_b128
        }
        __syncthreads();
        unsigned short* Wo = Wt + ((size_t)e << 20) + (size_t)(nb2 * 128) * kH + kb * 64;
        int k8 = (tid & 7) * 8;                  // this thread's 8-k chunk
#pragma unroll
        for (int pp = 0; pp < 4; ++pp) {
            int n = pp * 32 + (tid >> 3);        // 0..127 (output row)
            int key = ((n ^ (n >> 3)) & 7) << 2;
            uint4 q = *(const uint4*)&ldsw[n * 32 + (((tid & 7) * 4) ^ key)];
            *(uint4*)(Wo + (size_t)n * kH + k8) = q;   // short8, k-contiguous 16B
        }
        return;
    }
    // ---- router path: rid in 0..1023, 8 tokens/block (2 per wave) ----
    float* rwlds = (float*)smem;                 // 2048 16-B chunks
    int rid = bid - 1024;
    // stage rw -> LDS, chunk-XOR swizzled; global side dense (16 B/lane contiguous)
#pragma unroll
    for (int i = 0; i < 8; ++i) {
        int g = i * 256 + tid;                   // logical 16-B chunk id
        float4 v = *(const float4*)(rw + 4 * g);
        int pq = g ^ ((g >> 3) & 7);
        *(float4*)&rwlds[4 * pq] = v;
    }
    __syncthreads();
    int w = tid >> 6, lane = tid & 63;
    for (int tk = 0; tk < 2; ++tk) {
        int t = rid * 8 + w * 2 + tk;
        const float* xp = x + (size_t)t * kH;
        unsigned short* xop = xb + (size_t)t * kH;
        float pe[8];
#pragma unroll
        for (int e2 = 0; e2 < 8; ++e2) pe[e2] = 0.f;
#pragma unroll
        for (int j = 0; j < 4; ++j) {
            int h0 = j * 256 + lane * 4;
            float4 xv = *(const float4*)(xp + h0);
            ushort4 o;
            o.x = f2b(xv.x); o.y = f2b(xv.y); o.z = f2b(xv.z); o.w = f2b(xv.w);
            *(ushort4*)(xop + h0) = o;
            float xa[4] = {xv.x, xv.y, xv.z, xv.w};
#pragma unroll
            for (int cc = 0; cc < 4; ++cc) {
                int q0 = 2 * (h0 + cc);          // even chunk of rw row h
                int key = (q0 >> 3) & 7;         // = lane&7 (write-side function match)
                float4 w0 = *(const float4*)&rwlds[4 * (q0 ^ key)];
                float4 w1 = *(const float4*)&rwlds[4 * ((q0 + 1) ^ key)];
                float xs = xa[cc];
                pe[0] += xs * w0.x; pe[1] += xs * w0.y;
                pe[2] += xs * w0.z; pe[3] += xs * w0.w;
                pe[4] += xs * w1.x; pe[5] += xs * w1.y;
                pe[6] += xs * w1.z; pe[7] += xs * w1.w;
            }
        }
        // wave butterfly -> lane 0 holds full logit sums
#pragma unroll
        for (int s = 1; s < 64; s <<= 1)
#pragma unroll
            for (int e2 = 0; e2 < 8; ++e2) pe[e2] += __shfl_xor(pe[e2], s);
        if (lane == 0) {
            float m = pe[0] + rb[0]; int bi = 0;
#pragma unroll
            for (int e2 = 1; e2 < 8; ++e2) {     // first-max tie-break (strict >)
                float l = pe[e2] + rb[e2];
                if (l > m) { m = l; bi = e2; }
            }
            float sum = 0.f;
#pragma unroll
            for (int e2 = 0; e2 < 8; ++e2) sum += __expf(pe[e2] + rb[e2] - m);
            gate[t] = 1.0f / sum;                // softmax prob at argmax
            idx[t]  = bi;
        }
    }
}

// ---------------- K2: rank/permutation (pure histogram+perm; tail removed R15) -------
// One token/thread. Block-local LDS histogram -> local rank; ONE global atomic per
// (block, expert) on 128B-padded lines (256 total). Tile table derived in k_gemm.
__global__ __launch_bounds__(256) void k_rank(const int* __restrict__ idx,
                                              int* __restrict__ perm2,
                                              int* __restrict__ cnt) {
    __shared__ int lcnt[kE];
    __shared__ int lbase[kE];
    int tid = threadIdx.x;
    if (tid < kE) lcnt[tid] = 0;
    __syncthreads();
    int t = blockIdx.x * 256 + tid;
    int bi = idx[t];
    int lrank = atomicAdd(&lcnt[bi], 1);        // LDS atomic: local rank
    __syncthreads();
    if (tid < kE) lbase[tid] = atomicAdd(&cnt[tid * kCntStride], lcnt[tid]);
    __syncthreads();
    perm2[bi * kT + lbase[bi] + lrank] = t;     // sorted row -> token
}

// ---------------- K3: grouped GEMM, 128x128 tile, BK=64, mfma_f32_16x16x32_bf16 --------
// Each block derives its (expert, row-base) from an 8-iteration prefix over cnt
// (uniform L2 loads) — no tile table, no done-protocol. Core loop: A-tiles gathered
// on the fly from xb via perm2 into global_load_lds (pad rows read token 0, skipped
// in epilogue); 16-B chunk-XOR swizzle on the GLOBAL side; 3 blocks/CU; per-ks
// fragment loads.
constexpr int kBK = 64;

__global__ __launch_bounds__(256, 3) void k_gemm(const unsigned short* __restrict__ xb,
                                                 const unsigned short* __restrict__ Wt,
                                                 const float* __restrict__ eb,
                                                 const int* __restrict__ perm2,
                                                 const float* __restrict__ gate,
                                                 const int* __restrict__ cnt,
                                                 float* __restrict__ out) {
    int bm = blockIdx.x, bn = blockIdx.y;
    // derive (e, l0, ce) from cnt prefix
    int e = -1, l0 = 0, ce = 0, tilesum = 0;
#pragma unroll
    for (int ee = 0; ee < kE; ++ee) {
        int c = cnt[ee * kCntStride];
        int nt = (c + 127) >> 7;
        if (e < 0 && bm < tilesum + nt) { e = ee; l0 = (bm - tilesum) << 7; ce = c; }
        tilesum += nt;
    }
    if (e < 0) return;
    const int* pe = perm2 + e * kT;

    __shared__ __align__(16) unsigned short As[128 * kBK];   // 16 KB
    __shared__ __align__(16) unsigned short Bs[128 * kBK];   // 16 KB

    int tid = threadIdx.x;
    int wave = tid >> 6, lane = tid & 63;
    int wm = wave & 1, wn = wave >> 1;           // 2x2 waves over 128x128
    int quad = lane >> 4, l15 = lane & 15;

    floatx4 acc[4][4];
#pragma unroll
    for (int i = 0; i < 4; ++i)
#pragma unroll
        for (int j = 0; j < 4; ++j) acc[i][j] = floatx4{0.f, 0.f, 0.f, 0.f};

    // staging: wave stages rows [wave*32, wave*32+32), 4 issues of 8 rows each.
    int lrow8 = lane >> 3;                       // 0..7
    int lseg8 = (lane & 7) ^ lrow8;              // swizzled 16B chunk (global side)
    const unsigned short* aPj[4];
#pragma unroll
    for (int j = 0; j < 4; ++j) {
        int lr = l0 + wave * 32 + j * 8 + lrow8;
        int tok = (lr < ce) ? pe[lr] : 0;        // pad rows read token 0, skipped later
        aPj[j] = xb + (size_t)tok * kH + lseg8 * 8;
    }
    const unsigned short* bP = Wt + ((size_t)e << 20)
                             + (size_t)(bn * 128 + wave * 32 + lrow8) * kH + lseg8 * 8;
    unsigned short* lA = &As[(wave * 32) * kBK];
    unsigned short* lB = &Bs[(wave * 32) * kBK];

    for (int k0 = 0; k0 < kH; k0 += kBK) {
        __syncthreads();                         // prior iter's fragment reads complete
#pragma unroll
        for (int j = 0; j < 4; ++j) {
            GLDS16(aPj[j] + k0, lA + j * 8 * kBK);
            GLDS16(bP + (size_t)(j * 8) * kH + k0, lB + j * 8 * kBK);
        }
        __syncthreads();                         // drains vmcnt -> tile visible

        // fragment read chunk: global seg g = ks*4+quad at row l15 -> LDS seg g^(l15&7)
#pragma unroll
        for (int ks = 0; ks < 2; ++ks) {
            int sw = ((ks * 4 + quad) ^ (l15 & 7)) * 8;
            short8 af[4], bf[4];
#pragma unroll
            for (int i = 0; i < 4; ++i)
                af[i] = *(const short8*)&As[(wm * 64 + i * 16 + l15) * kBK + sw];
#pragma unroll
            for (int j = 0; j < 4; ++j)
                bf[j] = *(const short8*)&Bs[(wn * 64 + j * 16 + l15) * kBK + sw];
#pragma unroll
            for (int i = 0; i < 4; ++i)
#pragma unroll
                for (int j = 0; j < 4; ++j)
                    acc[i][j] = __builtin_amdgcn_mfma_f32_16x16x32_bf16(af[i], bf[j],
                                                                        acc[i][j], 0, 0, 0);
        }
    }

    // epilogue: C row = quad*4 + reg, col = lane&15 (verified m89/m91 mapping)
    int colbase = bn * 128 + wn * 64;
#pragma unroll
    for (int i = 0; i < 4; ++i) {
        int rl = l0 + wm * 64 + i * 16 + quad * 4;
#pragma unroll
        for (int rg = 0; rg < 4; ++rg) {
            int lr = rl + rg;
            if (lr >= ce) continue;         // pad row
            int tok = pe[lr];
            float g = gate[tok];
            float* op = out + (size_t)tok * kH;
#pragma unroll
            for (int j = 0; j < 4; ++j) {
                int col = colbase + j * 16 + l15;
                op[col] = g * (acc[i][j][rg] + eb[e * kH + col]);
            }
        }
    }
}

extern "C" void kernel_launch(void* const* d_in, const int* in_sizes, int n_in,
                              void* d_out, int out_size, void* d_ws, size_t ws_size,
                              hipStream_t stream) {
    const float* x  = (const float*)d_in[0];   // [T,H]
    const float* rw = (const float*)d_in[1];   // [H,E]
    const float* rb = (const float*)d_in[2];   // [E]
    const float* ew = (const float*)d_in[3];   // [E,H,H]
    const float* eb = (const float*)d_in[4];   // [E,H]
    float* out = (float*)d_out;                // [T,H]

    char* p = (char*)d_ws;
    unsigned short* Wt = (unsigned short*)p; p += (size_t)kE * kH * kH * 2;   // 16 MB
    unsigned short* xb = (unsigned short*)p; p += (size_t)kT * kH * 2;        // 16 MB
    float* gate  = (float*)p; p += (size_t)kT * 4;
    int* idx     = (int*)p;   p += (size_t)kT * 4;
    int* perm2   = (int*)p;   p += (size_t)kE * kT * 4;                       // 256 KB
    int* cnt     = (int*)p;   p += kE * kCntStride * 4;   // 128B-padded counters

    k_prep<<<2048, 256, 0, stream>>>(ew, Wt, x, xb, rw, rb, gate, idx, cnt);
    k_rank<<<kT / 256, 256, 0, stream>>>(idx, perm2, cnt);
    dim3 gg(kMaxTiles, kH / 128);
    k_gemm<<<gg, 256, 0, stream>>>(xb, Wt, eb, perm2, gate, cnt, out);
}

// Round 10
// 151.427 us; speedup vs baseline: 1.3147x; 1.3147x over previous
//
#include <hip/hip_runtime.h>

// Problem constants (B=4, S=2048 -> T=8192 tokens; H=1024; E=8 experts)
constexpr int kT = 8192;
constexpr int kH = 1024;
constexpr int kE = 8;
constexpr int kMaxTiles = 72;     // kT/128 + kE
constexpr int kCntStride = 32;    // pad expert counters to separate 128B cache lines

typedef short short8 __attribute__((ext_vector_type(8)));
typedef float floatx4 __attribute__((ext_vector_type(4)));

__device__ inline unsigned short f2b(float f) {
    union { float f; unsigned int u; } v; v.f = f;
    unsigned int r = v.u + 0x7FFFu + ((v.u >> 16) & 1u);  // round-to-nearest-even
    return (unsigned short)(r >> 16);
}

#define GLDS16(gp, lp)                                                                  \
    __builtin_amdgcn_global_load_lds(                                                   \
        (const __attribute__((address_space(1))) unsigned int*)(gp),                    \
        (__attribute__((address_space(3))) unsigned int*)(lp), 16, 0, 0)

// ---------------- K1: FUSED prep (R17 = R14 exactly) ----------------
// R17 post-mortem of R16: adding __launch_bounds__(256,4) as "insurance" CAUSED
// scratch spilling — FETCH/WRITE both +73MB (symmetric = spill round-trips),
// VGPR_Count 64, prep 33->74us, total 199us. Lesson: never add a launch-bounds
// floor without checking -Rpass resource usage; the cap constrains the allocator.
// Reverted to plain __launch_bounds__(256) — the R14 config whose prep ran <40us
// (total 156.3, best known). bid [0,1024) = transpose (wide-LDS, b128 both sides),
// [1024,2048) = router (rw staged in LDS, 8 tokens/block).
__global__ __launch_bounds__(256) void k_prep(const float* __restrict__ W,
                                              unsigned short* __restrict__ Wt,
                                              const float* __restrict__ x,
                                              unsigned short* __restrict__ xb,
                                              const float* __restrict__ rw,
                                              const float* __restrict__ rb,
                                              float* __restrict__ gate,
                                              int* __restrict__ idx,
                                              int* __restrict__ cnt) {
    __shared__ __align__(16) char smem[32768];
    int bid = blockIdx.x, tid = threadIdx.x;
    if (bid == 0 && tid < kE) cnt[tid * kCntStride] = 0;   // zero padded counters
    if (bid < 1024) {
        // ---- transpose path: 64k x 128n per block (R14 wide-LDS scheme) ----
        unsigned int* ldsw = (unsigned int*)smem;   // [128][32] dwords, swizzled (16KB)
        int tb = bid;
        int e = tb >> 7, kb = (tb >> 3) & 15, nb2 = tb & 7;
        const float* Wp = W + ((size_t)e << 20) + (size_t)(kb * 64) * kH + nb2 * 128;
        int c = (tid & 31) * 4;                  // n base (0..124)
        int rr = tid >> 5;                       // 0..7 (8-k slab)
        unsigned int dw[4][4];                   // [i = k-pair][j = n offset]
#pragma unroll
        for (int i = 0; i < 4; ++i) {
            int r0 = rr * 8 + i * 2;
            float4 v0 = *(const float4*)(Wp + (size_t)r0 * kH + c);
            float4 v1 = *(const float4*)(Wp + (size_t)(r0 + 1) * kH + c);
            dw[i][0] = (unsigned int)f2b(v0.x) | ((unsigned int)f2b(v1.x) << 16);
            dw[i][1] = (unsigned int)f2b(v0.y) | ((unsigned int)f2b(v1.y) << 16);
            dw[i][2] = (unsigned int)f2b(v0.z) | ((unsigned int)f2b(v1.z) << 16);
            dw[i][3] = (unsigned int)f2b(v0.w) | ((unsigned int)f2b(v1.w) << 16);
        }
#pragma unroll
        for (int j = 0; j < 4; ++j) {
            int n = c + j;
            int key = ((n ^ (n >> 3)) & 7) << 2;
            uint4 q{dw[0][j], dw[1][j], dw[2][j], dw[3][j]};   // logical dw rr*4..+3
            *(uint4*)&ldsw[n * 32 + ((rr * 4) ^ key)] = q;     // ds_write_b128
        }
        __syncthreads();
        unsigned short* Wo = Wt + ((size_t)e << 20) + (size_t)(nb2 * 128) * kH + kb * 64;
        int k8 = (tid & 7) * 8;                  // this thread's 8-k chunk
#pragma unroll
        for (int pp = 0; pp < 4; ++pp) {
            int n = pp * 32 + (tid >> 3);        // 0..127 (output row)
            int key = ((n ^ (n >> 3)) & 7) << 2;
            uint4 q = *(const uint4*)&ldsw[n * 32 + (((tid & 7) * 4) ^ key)];
            *(uint4*)(Wo + (size_t)n * kH + k8) = q;   // short8, k-contiguous 16B
        }
        return;
    }
    // ---- router path: rid in 0..1023, 8 tokens/block (2 per wave) ----
    float* rwlds = (float*)smem;                 // 2048 16-B chunks
    int rid = bid - 1024;
    // stage rw -> LDS, chunk-XOR swizzled; global side dense (16 B/lane contiguous)
#pragma unroll
    for (int i = 0; i < 8; ++i) {
        int g = i * 256 + tid;                   // logical 16-B chunk id
        float4 v = *(const float4*)(rw + 4 * g);
        int pq = g ^ ((g >> 3) & 7);
        *(float4*)&rwlds[4 * pq] = v;
    }
    __syncthreads();
    int w = tid >> 6, lane = tid & 63;
    for (int tk = 0; tk < 2; ++tk) {
        int t = rid * 8 + w * 2 + tk;
        const float* xp = x + (size_t)t * kH;
        unsigned short* xop = xb + (size_t)t * kH;
        float pe[8];
#pragma unroll
        for (int e2 = 0; e2 < 8; ++e2) pe[e2] = 0.f;
#pragma unroll
        for (int j = 0; j < 4; ++j) {
            int h0 = j * 256 + lane * 4;
            float4 xv = *(const float4*)(xp + h0);
            ushort4 o;
            o.x = f2b(xv.x); o.y = f2b(xv.y); o.z = f2b(xv.z); o.w = f2b(xv.w);
            *(ushort4*)(xop + h0) = o;
            float xa[4] = {xv.x, xv.y, xv.z, xv.w};
#pragma unroll
            for (int cc = 0; cc < 4; ++cc) {
                int q0 = 2 * (h0 + cc);          // even chunk of rw row h
                int key = (q0 >> 3) & 7;         // = lane&7 (write-side function match)
                float4 w0 = *(const float4*)&rwlds[4 * (q0 ^ key)];
                float4 w1 = *(const float4*)&rwlds[4 * ((q0 + 1) ^ key)];
                float xs = xa[cc];
                pe[0] += xs * w0.x; pe[1] += xs * w0.y;
                pe[2] += xs * w0.z; pe[3] += xs * w0.w;
                pe[4] += xs * w1.x; pe[5] += xs * w1.y;
                pe[6] += xs * w1.z; pe[7] += xs * w1.w;
            }
        }
        // wave butterfly -> lane 0 holds full logit sums
#pragma unroll
        for (int s = 1; s < 64; s <<= 1)
#pragma unroll
            for (int e2 = 0; e2 < 8; ++e2) pe[e2] += __shfl_xor(pe[e2], s);
        if (lane == 0) {
            float m = pe[0] + rb[0]; int bi = 0;
#pragma unroll
            for (int e2 = 1; e2 < 8; ++e2) {     // first-max tie-break (strict >)
                float l = pe[e2] + rb[e2];
                if (l > m) { m = l; bi = e2; }
            }
            float sum = 0.f;
#pragma unroll
            for (int e2 = 0; e2 < 8; ++e2) sum += __expf(pe[e2] + rb[e2] - m);
            gate[t] = 1.0f / sum;                // softmax prob at argmax
            idx[t]  = bi;
        }
    }
}

// ---------------- K2: rank/permutation (pure histogram+perm) ----------------
// One token/thread. Block-local LDS histogram -> local rank; ONE global atomic per
// (block, expert) on 128B-padded lines (256 total). Tile table derived in k_gemm.
__global__ __launch_bounds__(256) void k_rank(const int* __restrict__ idx,
                                              int* __restrict__ perm2,
                                              int* __restrict__ cnt) {
    __shared__ int lcnt[kE];
    __shared__ int lbase[kE];
    int tid = threadIdx.x;
    if (tid < kE) lcnt[tid] = 0;
    __syncthreads();
    int t = blockIdx.x * 256 + tid;
    int bi = idx[t];
    int lrank = atomicAdd(&lcnt[bi], 1);        // LDS atomic: local rank
    __syncthreads();
    if (tid < kE) lbase[tid] = atomicAdd(&cnt[tid * kCntStride], lcnt[tid]);
    __syncthreads();
    perm2[bi * kT + lbase[bi] + lrank] = t;     // sorted row -> token
}

// ---------------- K3: grouped GEMM, 128x128 tile, BK=64, mfma_f32_16x16x32_bf16 --------
// Each block derives its (expert, row-base) from an 8-iteration prefix over cnt
// (uniform L2 loads) — no tile table, no done-protocol. Core loop: A-tiles gathered
// on the fly from xb via perm2 into global_load_lds (pad rows read token 0, skipped
// in epilogue); 16-B chunk-XOR swizzle on the GLOBAL side; 3 blocks/CU; per-ks
// fragment loads.
constexpr int kBK = 64;

__global__ __launch_bounds__(256, 3) void k_gemm(const unsigned short* __restrict__ xb,
                                                 const unsigned short* __restrict__ Wt,
                                                 const float* __restrict__ eb,
                                                 const int* __restrict__ perm2,
                                                 const float* __restrict__ gate,
                                                 const int* __restrict__ cnt,
                                                 float* __restrict__ out) {
    int bm = blockIdx.x, bn = blockIdx.y;
    // derive (e, l0, ce) from cnt prefix
    int e = -1, l0 = 0, ce = 0, tilesum = 0;
#pragma unroll
    for (int ee = 0; ee < kE; ++ee) {
        int c = cnt[ee * kCntStride];
        int nt = (c + 127) >> 7;
        if (e < 0 && bm < tilesum + nt) { e = ee; l0 = (bm - tilesum) << 7; ce = c; }
        tilesum += nt;
    }
    if (e < 0) return;
    const int* pe = perm2 + e * kT;

    __shared__ __align__(16) unsigned short As[128 * kBK];   // 16 KB
    __shared__ __align__(16) unsigned short Bs[128 * kBK];   // 16 KB

    int tid = threadIdx.x;
    int wave = tid >> 6, lane = tid & 63;
    int wm = wave & 1, wn = wave >> 1;           // 2x2 waves over 128x128
    int quad = lane >> 4, l15 = lane & 15;

    floatx4 acc[4][4];
#pragma unroll
    for (int i = 0; i < 4; ++i)
#pragma unroll
        for (int j = 0; j < 4; ++j) acc[i][j] = floatx4{0.f, 0.f, 0.f, 0.f};

    // staging: wave stages rows [wave*32, wave*32+32), 4 issues of 8 rows each.
    int lrow8 = lane >> 3;                       // 0..7
    int lseg8 = (lane & 7) ^ lrow8;              // swizzled 16B chunk (global side)
    const unsigned short* aPj[4];
#pragma unroll
    for (int j = 0; j < 4; ++j) {
        int lr = l0 + wave * 32 + j * 8 + lrow8;
        int tok = (lr < ce) ? pe[lr] : 0;        // pad rows read token 0, skipped later
        aPj[j] = xb + (size_t)tok * kH + lseg8 * 8;
    }
    const unsigned short* bP = Wt + ((size_t)e << 20)
                             + (size_t)(bn * 128 + wave * 32 + lrow8) * kH + lseg8 * 8;
    unsigned short* lA = &As[(wave * 32) * kBK];
    unsigned short* lB = &Bs[(wave * 32) * kBK];

    for (int k0 = 0; k0 < kH; k0 += kBK) {
        __syncthreads();                         // prior iter's fragment reads complete
#pragma unroll
        for (int j = 0; j < 4; ++j) {
            GLDS16(aPj[j] + k0, lA + j * 8 * kBK);
            GLDS16(bP + (size_t)(j * 8) * kH + k0, lB + j * 8 * kBK);
        }
        __syncthreads();                         // drains vmcnt -> tile visible

        // fragment read chunk: global seg g = ks*4+quad at row l15 -> LDS seg g^(l15&7)
#pragma unroll
        for (int ks = 0; ks < 2; ++ks) {
            int sw = ((ks * 4 + quad) ^ (l15 & 7)) * 8;
            short8 af[4], bf[4];
#pragma unroll
            for (int i = 0; i < 4; ++i)
                af[i] = *(const short8*)&As[(wm * 64 + i * 16 + l15) * kBK + sw];
#pragma unroll
            for (int j = 0; j < 4; ++j)
                bf[j] = *(const short8*)&Bs[(wn * 64 + j * 16 + l15) * kBK + sw];
#pragma unroll
            for (int i = 0; i < 4; ++i)
#pragma unroll
                for (int j = 0; j < 4; ++j)
                    acc[i][j] = __builtin_amdgcn_mfma_f32_16x16x32_bf16(af[i], bf[j],
                                                                        acc[i][j], 0, 0, 0);
        }
    }

    // epilogue: C row = quad*4 + reg, col = lane&15 (verified m89/m91 mapping)
    int colbase = bn * 128 + wn * 64;
#pragma unroll
    for (int i = 0; i < 4; ++i) {
        int rl = l0 + wm * 64 + i * 16 + quad * 4;
#pragma unroll
        for (int rg = 0; rg < 4; ++rg) {
            int lr = rl + rg;
            if (lr >= ce) continue;         // pad row
            int tok = pe[lr];
            float g = gate[tok];
            float* op = out + (size_t)tok * kH;
#pragma unroll
            for (int j = 0; j < 4; ++j) {
                int col = colbase + j * 16 + l15;
                op[col] = g * (acc[i][j][rg] + eb[e * kH + col]);
            }
        }
    }
}

extern "C" void kernel_launch(void* const* d_in, const int* in_sizes, int n_in,
                              void* d_out, int out_size, void* d_ws, size_t ws_size,
                              hipStream_t stream) {
    const float* x  = (const float*)d_in[0];   // [T,H]
    const float* rw = (const float*)d_in[1];   // [H,E]
    const float* rb = (const float*)d_in[2];   // [E]
    const float* ew = (const float*)d_in[3];   // [E,H,H]
    const float* eb = (const float*)d_in[4];   // [E,H]
    float* out = (float*)d_out;                // [T,H]

    char* p = (char*)d_ws;
    unsigned short* Wt = (unsigned short*)p; p += (size_t)kE * kH * kH * 2;   // 16 MB
    unsigned short* xb = (unsigned short*)p; p += (size_t)kT * kH * 2;        // 16 MB
    float* gate  = (float*)p; p += (size_t)kT * 4;
    int* idx     = (int*)p;   p += (size_t)kT * 4;
    int* perm2   = (int*)p;   p += (size_t)kE * kT * 4;                       // 256 KB
    int* cnt     = (int*)p;   p += kE * kCntStride * 4;   // 128B-padded counters

    k_prep<<<2048, 256, 0, stream>>>(ew, Wt, x, xb, rw, rb, gate, idx, cnt);
    k_rank<<<kT / 256, 256, 0, stream>>>(idx, perm2, cnt);
    dim3 gg(kMaxTiles, kH / 128);
    k_gemm<<<gg, 256, 0, stream>>>(xb, Wt, eb, perm2, gate, cnt, out);
}